// Round 8
// baseline (1067.648 us; speedup 1.0000x reference)
//
#include <hip/hip_runtime.h>

// ---------------- constants ----------------
constexpr int kE   = 2048;   // entities
constexpr int kS   = 32;     // sequence length
constexpr int kD   = 256;    // ENT_DIM == REL_DIM == H
constexpr int kK   = 512;    // concat K (for lin)
constexpr int kREL = 500;
constexpr int kN   = 1024;   // triples per polarity

typedef unsigned short u16;
typedef __attribute__((ext_vector_type(8))) _Float16 f16x8;
typedef __attribute__((ext_vector_type(4))) float    f32x4;
typedef __attribute__((ext_vector_type(4))) unsigned short us4;

static __device__ __forceinline__ u16 f2h(float f) {
  _Float16 h = (_Float16)f;
  return __builtin_bit_cast(u16, h);
}
static __device__ __forceinline__ float h2f(u16 v) {
  _Float16 h = __builtin_bit_cast(_Float16, v);
  return (float)h;
}
static __device__ __forceinline__ float sigf(float x) { return 1.f / (1.f + __expf(-x)); }
static __device__ __forceinline__ float tanhfast(float x) {
  float e = __expf(2.f * x);
  return 1.f - 2.f / (e + 1.f);
}

// ---------------- prep: weights -> fp16 ----------------
// j-order (gate-interleaved): j -> gate g=(j>>4)&3, unit u=(j>>6)*16+(j&15), orig row R=g*256+u
// Wihr[d][j][256k] row-major; Whhv[d][c(8)][j(1024)][32k] chunk-major; Wlin[256][512] row-major
__global__ void prep_weights(const float* __restrict__ Wih_f, const float* __restrict__ Whh_f,
                             const float* __restrict__ Wih_b, const float* __restrict__ Whh_b,
                             const float* __restrict__ Wlin_in,
                             u16* __restrict__ Wihr, u16* __restrict__ Whhv,
                             u16* __restrict__ Wlin) {
  int idx = blockIdx.x * 256 + threadIdx.x;
  if (idx < 65536) {                       // Wihr: 2 x 32768 16B-units
    int d = idx >> 15;
    int j = (idx & 32767) >> 5;
    int k = (idx & 31) * 8;
    int g = (j >> 4) & 3, u = (j >> 6) * 16 + (j & 15);
    int R = g * 256 + u;
    const float* src = (d ? Wih_b : Wih_f) + R * 256 + k;
    ushort oa[8];
#pragma unroll
    for (int i = 0; i < 8; i++) oa[i] = f2h(src[i]);
    *(uint4*)((char*)Wihr + (size_t)idx * 16) = *(uint4*)oa;
  } else if (idx < 131072) {               // Whhv: 2 x 8 x 4096 16B-units
    int i = idx - 65536;
    int d = i >> 15;
    int rem = i & 32767;
    int c = rem >> 12;
    int P = (rem & 4095) * 16;
    int j = P >> 6, b = P & 63;
    int k = c * 32 + (b >> 1);
    int g = (j >> 4) & 3, u = (j >> 6) * 16 + (j & 15);
    int R = g * 256 + u;
    const float* src = (d ? Whh_b : Whh_f) + R * 256 + k;
    ushort oa[8];
#pragma unroll
    for (int ii = 0; ii < 8; ii++) oa[ii] = f2h(src[ii]);
    *(uint4*)((char*)Whhv + (size_t)i * 16) = *(uint4*)oa;
  } else if (idx < 131072 + 16384) {       // Wlin
    int q = (idx - 131072) * 8;
#pragma unroll
    for (int i = 0; i < 8; i++) Wlin[q + i] = f2h(Wlin_in[q + i]);
  }
}

// ---------------- gather x: x16[s][e][k] = fp16(ent_embed[neighbors[e][s]][k]) ----------------
__global__ void gather_x(const int* __restrict__ neighbors, const float* __restrict__ ent,
                         u16* __restrict__ x16) {
  const int tot = kS * kE * kD / 4;
  for (int i = blockIdx.x * blockDim.x + threadIdx.x; i < tot; i += gridDim.x * blockDim.x) {
    int k4 = i & 63;
    int row = i >> 6;               // s*kE + e
    int e = row & (kE - 1);
    int s = row >> 11;
    int nb = neighbors[e * kS + s];
    float4 v = *(const float4*)(ent + (size_t)nb * kD + k4 * 4);
    ushort4 o;
    o.x = f2h(v.x); o.y = f2h(v.y); o.z = f2h(v.z); o.w = f2h(v.w);
    *(ushort4*)(x16 + (size_t)row * kD + k4 * 4) = o;
  }
}

// ---------------- xgemm: gates_x = x @ W_ih^T + bias, for tt in [0,T) ----------------
// gx[dir][tt][e][u][4g] fp16 (bias folded in). grid (T*32, 4, 2), 256 thr.
__global__ __launch_bounds__(256) void xgemm(
    const u16* __restrict__ x16, const u16* __restrict__ Wihr,
    const float* __restrict__ b_f, const float* __restrict__ b_b,
    u16* __restrict__ gx, int t0, int T) {
  __shared__ __align__(16) char smem[40960];
  u16* As = (u16*)smem;
  u16* Bs = (u16*)(smem + 8192);
  const int tid = threadIdx.x, lane = tid & 63, w = tid >> 6;
  const int l15 = lane & 15, lq = lane >> 4;
  const int row0 = blockIdx.x * 64;
  const int y = blockIdx.y;
  const int dir = blockIdx.z;
  const int tt = row0 >> 11;
  const int e0 = row0 & 2047;
  const int s = dir ? (31 - (t0 + tt)) : (t0 + tt);
  const u16* Ab = x16 + ((size_t)s * kE + e0) * kD;
  const u16* Bb = Wihr + ((size_t)dir * 1024 + y * 256) * kD;
  const float* bd = dir ? b_b : b_f;
  const int u = (y * 4 + w) * 16 + l15;
  float bb4[4];
#pragma unroll
  for (int n = 0; n < 4; n++) bb4[n] = bd[n * 256 + u];

  f32x4 acc[4][4];
#pragma unroll
  for (int m = 0; m < 4; m++)
#pragma unroll
    for (int n = 0; n < 4; n++) acc[m][n] = (f32x4){0.f, 0.f, 0.f, 0.f};

  for (int ch = 0; ch < 4; ++ch) {
    const int k0 = ch * 64;
    __syncthreads();
#pragma unroll
    for (int i = 0; i < 2; i++) {
      int idx = tid + i * 256;
      int row = idx >> 3, c8 = idx & 7;
      uint4 v = *(const uint4*)(Ab + (size_t)row * kD + k0 + c8 * 8);
      *(uint4*)((char*)As + row * 128 + ((c8 * 16) ^ ((row & 7) << 4))) = v;
    }
#pragma unroll
    for (int i = 0; i < 8; i++) {
      int idx = tid + i * 256;
      int j = idx >> 3, c8 = idx & 7;
      uint4 v = *(const uint4*)(Bb + (size_t)j * kD + k0 + c8 * 8);
      *(uint4*)((char*)Bs + j * 128 + ((c8 * 16) ^ ((j & 7) << 4))) = v;
    }
    __syncthreads();
#pragma unroll
    for (int ks = 0; ks < 2; ++ks) {
      const int kb = ks * 64 + lq * 16;
      f16x8 a[4], b[4];
#pragma unroll
      for (int m = 0; m < 4; m++) {
        int row = m * 16 + l15;
        a[m] = *(const f16x8*)((const char*)As + row * 128 + (kb ^ ((row & 7) << 4)));
      }
#pragma unroll
      for (int n = 0; n < 4; n++) {
        int row = w * 64 + n * 16 + l15;
        b[n] = *(const f16x8*)((const char*)Bs + row * 128 + (kb ^ ((row & 7) << 4)));
      }
#pragma unroll
      for (int m = 0; m < 4; m++)
#pragma unroll
        for (int n = 0; n < 4; n++)
          acc[m][n] = __builtin_amdgcn_mfma_f32_16x16x32_f16(a[m], b[n], acc[m][n], 0, 0, 0);
    }
  }

  // store (+bias): g == n, one us4 per (m,r); non-temporal (read-once stream)
  u16* out = gx + (((size_t)dir * T + tt) * kE) * 1024;
#pragma unroll
  for (int m = 0; m < 4; m++)
#pragma unroll
    for (int r = 0; r < 4; r++) {
      int e = e0 + m * 16 + lq * 4 + r;
      us4 o;
      o[0] = f2h(acc[m][0][r] + bb4[0]); o[1] = f2h(acc[m][1][r] + bb4[1]);
      o[2] = f2h(acc[m][2][r] + bb4[2]); o[3] = f2h(acc[m][3][r] + bb4[3]);
      __builtin_nontemporal_store(o, (us4*)(out + ((size_t)e * 256 + u) * 4));
    }
}

// ---------------- recurrent kernel: h-GEMM (K=256) + gate combine, T steps ----------------
// grid 128 = 2dir x 64 etiles(32e); 512 thr = 8 waves; wave = 32e x 128j, TWO passes of 64j
// (pass uu = 4 gates of unit group w*2+uu) so acc is only [2][4]. Register budget ~116.
__global__ __launch_bounds__(512, 2) void lstm_rec(
    const u16* __restrict__ gx, const u16* __restrict__ Whhv,
    u16* __restrict__ hio, float* __restrict__ cio, int t0, int T) {
  __shared__ __align__(16) char hb[2][16384];
  const int tid = threadIdx.x, lane = tid & 63, w = tid >> 6;
  const int l15 = lane & 15, lq = lane >> 4;
  const int bid = blockIdx.x;
  const int xcd = bid & 7;
  const int dir = xcd >> 2;                       // dir-per-XCD-half (W/XCD = 512 KB)
  const int e0 = ((bid >> 3) * 4 + (xcd & 3)) * 32;

  const char* Wd = (const char*)Whhv + (size_t)dir * 524288;   // [8c][1024j][64B]
  const u16* gxd = gx + (size_t)dir * T * kE * 1024;

  // init h into hb[0] (swizzled): 1024 uint4 items
#pragma unroll
  for (int q = 0; q < 2; q++) {
    int idx = tid + q * 512;
    int row = idx >> 5, c16 = idx & 31;
    uint4 v = {0, 0, 0, 0};
    if (t0 > 0) v = *(const uint4*)(hio + ((size_t)dir * kE + e0 + row) * kD + c16 * 8);
    *(uint4*)(hb[0] + row * 512 + ((c16 * 16) ^ ((row & 7) << 4))) = v;
  }
  float creg[2][2][4];
#pragma unroll
  for (int m = 0; m < 2; m++)
#pragma unroll
    for (int uu = 0; uu < 2; uu++)
#pragma unroll
      for (int r = 0; r < 4; r++) {
        int u = (w * 2 + uu) * 16 + l15;
        creg[m][uu][r] = (t0 > 0)
          ? cio[((size_t)dir * kE + e0 + m * 16 + lq * 4 + r) * kD + u] : 0.f;
      }
  __syncthreads();

  int cur = 0;
  for (int t = 0; t < T; t++) {
    const char* hs = hb[cur];
    char* hn = hb[cur ^ 1];
    const u16* gp = gxd + (size_t)t * kE * 1024;
    const bool hOut = (t == T - 1);

    // prefetch gx for BOTH passes (pass-1's arrives during pass-0 GEMM)
    us4 G0[2][4], G1[2][4];
#pragma unroll
    for (int m = 0; m < 2; m++)
#pragma unroll
      for (int r = 0; r < 4; r++) {
        size_t e = (size_t)(e0 + m * 16 + lq * 4 + r);
        G0[m][r] = __builtin_nontemporal_load(
            (const us4*)(gp + e * 1024 + ((w * 2 + 0) * 16 + l15) * 4));
        G1[m][r] = __builtin_nontemporal_load(
            (const us4*)(gp + e * 1024 + ((w * 2 + 1) * 16 + l15) * 4));
      }

#pragma unroll
    for (int uu = 0; uu < 2; uu++) {
      const int u = (w * 2 + uu) * 16 + l15;
      // init acc from gx (bias already folded by xgemm)
      f32x4 acc[2][4];
#pragma unroll
      for (int m = 0; m < 2; m++)
#pragma unroll
        for (int g = 0; g < 4; g++)
#pragma unroll
          for (int r = 0; r < 4; r++)
            acc[m][g][r] = h2f(uu ? G1[m][r][g] : G0[m][r][g]);

      // GEMM over K=256 (8 chunks of 32), W double-buffered in registers
      const int jb = (w * 128 + uu * 64 + l15) * 64 + lq * 16;  // byte in [j][64B] + n*1024 + c*65536
      f16x8 wA[4], wB[4];
#pragma unroll
      for (int n = 0; n < 4; n++)
        wA[n] = *(const f16x8*)(Wd + jb + n * 1024);
#pragma unroll
      for (int c = 0; c < 8; c++) {
        if (c + 1 < 8) {
#pragma unroll
          for (int n = 0; n < 4; n++) {
            f16x8 v = *(const f16x8*)(Wd + (size_t)(c + 1) * 65536 + jb + n * 1024);
            if (c & 1) wA[n] = v; else wB[n] = v;
          }
        }
        const int sb = (c * 32 + lq * 8) * 2;
        f16x8 a0, a1;
        { int row = l15;      a0 = *(const f16x8*)(hs + row * 512 + (sb ^ ((row & 7) << 4))); }
        { int row = 16 + l15; a1 = *(const f16x8*)(hs + row * 512 + (sb ^ ((row & 7) << 4))); }
#pragma unroll
        for (int n = 0; n < 4; n++) {
          const f16x8 wc = (c & 1) ? wB[n] : wA[n];
          acc[0][n] = __builtin_amdgcn_mfma_f32_16x16x32_f16(a0, wc, acc[0][n], 0, 0, 0);
          acc[1][n] = __builtin_amdgcn_mfma_f32_16x16x32_f16(a1, wc, acc[1][n], 0, 0, 0);
        }
      }

      // gate combine for unit group uu
#pragma unroll
      for (int m = 0; m < 2; m++)
#pragma unroll
        for (int r = 0; r < 4; r++) {
          float gi = acc[m][0][r];
          float gf = acc[m][1][r];
          float gg = acc[m][2][r];
          float go = acc[m][3][r];
          float cn = sigf(gf) * creg[m][uu][r] + sigf(gi) * tanhfast(gg);
          creg[m][uu][r] = cn;
          u16 hv = f2h(sigf(go) * tanhfast(cn));
          int row = m * 16 + lq * 4 + r;
          *(u16*)(hn + row * 512 + ((u * 2) ^ ((row & 7) << 4))) = hv;
          if (hOut) hio[((size_t)dir * kE + e0 + row) * kD + u] = hv;
        }
    }
    __syncthreads();
    cur ^= 1;
  }

  if (t0 + T < kS) {
#pragma unroll
    for (int m = 0; m < 2; m++)
#pragma unroll
      for (int uu = 0; uu < 2; uu++)
#pragma unroll
        for (int r = 0; r < 4; r++) {
          int u = (w * 2 + uu) * 16 + l15;
          cio[((size_t)dir * kE + e0 + m * 16 + lq * 4 + r) * kD + u] = creg[m][uu][r];
        }
  }
}

// ---------------- shared MFMA GEMM tile (used by lin): 64 rows x 256 cols, K=512 ----------------
static __device__ __forceinline__ void gemm_tile(
    const u16* __restrict__ Alo, const u16* __restrict__ Ahi,
    const u16* __restrict__ W, int e0,
    u16* As, u16* Bs, f32x4 (&acc)[4][4]) {
  const int tid = threadIdx.x;
  const int lane = tid & 63;
  const int w = tid >> 6;
#pragma unroll
  for (int m = 0; m < 4; m++)
#pragma unroll
    for (int n = 0; n < 4; n++) acc[m][n] = (f32x4){0.f, 0.f, 0.f, 0.f};

  for (int ch = 0; ch < 8; ++ch) {
    const int k0 = ch * 64;
    __syncthreads();
    const u16* Asrc = (k0 < 256) ? Alo : Ahi;
    const int kbase = (k0 < 256) ? k0 : (k0 - 256);
#pragma unroll
    for (int i = 0; i < 2; i++) {
      int idx = tid + i * 256;
      int row = idx >> 3, c8 = idx & 7;
      uint4 v = *(const uint4*)(Asrc + (size_t)(e0 + row) * 256 + kbase + c8 * 8);
      *(uint4*)((char*)As + row * 128 + ((c8 * 16) ^ ((row & 7) << 4))) = v;
    }
#pragma unroll
    for (int i = 0; i < 8; i++) {
      int idx = tid + i * 256;
      int j = idx >> 3, c8 = idx & 7;
      uint4 v = *(const uint4*)(W + (size_t)j * kK + k0 + c8 * 8);
      *(uint4*)((char*)Bs + j * 128 + ((c8 * 16) ^ ((j & 7) << 4))) = v;
    }
    __syncthreads();
#pragma unroll
    for (int ks = 0; ks < 2; ++ks) {
      const int kb = ks * 64 + (lane >> 4) * 16;
      f16x8 a[4], b[4];
#pragma unroll
      for (int m = 0; m < 4; m++) {
        int row = m * 16 + (lane & 15);
        a[m] = *(const f16x8*)((const char*)As + row * 128 + (kb ^ ((row & 7) << 4)));
      }
#pragma unroll
      for (int n = 0; n < 4; n++) {
        int row = w * 64 + n * 16 + (lane & 15);
        b[n] = *(const f16x8*)((const char*)Bs + row * 128 + (kb ^ ((row & 7) << 4)));
      }
#pragma unroll
      for (int m = 0; m < 4; m++)
#pragma unroll
        for (int n = 0; n < 4; n++)
          acc[m][n] = __builtin_amdgcn_mfma_f32_16x16x32_f16(a[m], b[n], acc[m][n], 0, 0, 0);
    }
  }
}

// ---------------- lin = [h_f | h_b] @ W_lin^T + b_lin ----------------
__global__ __launch_bounds__(256) void lin_kernel(
    const u16* __restrict__ hf, const u16* __restrict__ hb,
    const u16* __restrict__ Wl, const float* __restrict__ b_lin,
    float* __restrict__ lin) {
  __shared__ __align__(16) char smem[40960];
  u16* As = (u16*)smem;
  u16* Bs = (u16*)(smem + 8192);
  const int tid = threadIdx.x, lane = tid & 63, w = tid >> 6;
  const int e0 = blockIdx.x * 64;
  f32x4 acc[4][4];
  gemm_tile(hf, hb, Wl, e0, As, Bs, acc);
#pragma unroll
  for (int m = 0; m < 4; m++)
#pragma unroll
    for (int n = 0; n < 4; n++)
#pragma unroll
      for (int r = 0; r < 4; r++) {
        int e = e0 + m * 16 + (lane >> 4) * 4 + r;
        int col = w * 64 + n * 16 + (lane & 15);
        lin[(size_t)e * 256 + col] = acc[m][n][r] + b_lin[col];
      }
}

// ---------------- BatchNorm stats (training mode, biased var) ----------------
__global__ void bn_stats(const float* __restrict__ lin, float* __restrict__ part) {
  int b = blockIdx.x, c = threadIdx.x;  // grid 64, each 32 rows
  float s = 0.f, s2 = 0.f;
  for (int e = b * 32; e < b * 32 + 32; ++e) {
    float x = lin[(size_t)e * 256 + c];
    s += x; s2 += x * x;
  }
  part[b * 256 + c] = s;
  part[64 * 256 + b * 256 + c] = s2;
}

// ---------------- BN finalize (inline) + tanh ----------------
__global__ void bn_apply(const float* __restrict__ lin, const float* __restrict__ part,
                         const float* __restrict__ gamma, const float* __restrict__ beta,
                         float* __restrict__ ctx) {
  int c = threadIdx.x;                   // grid 256, each 8 rows
  float s = 0.f, s2 = 0.f;
  for (int b = 0; b < 64; b++) { s += part[b * 256 + c]; s2 += part[64 * 256 + b * 256 + c]; }
  float mu = s * (1.f / 2048.f);
  float rsig = rsqrtf(s2 * (1.f / 2048.f) - mu * mu + 1e-5f);
  float ga = gamma[c], be = beta[c];
  int e0 = blockIdx.x * 8;
  for (int e = e0; e < e0 + 8; ++e) {
    float x = lin[(size_t)e * 256 + c];
    ctx[(size_t)e * 256 + c] = tanhf(ga * (x - mu) * rsig + be);
  }
}

// ---------------- relation grouping: count+scan+scatter in ONE block ----------------
__global__ void group_rel(const int* __restrict__ pr, const int* __restrict__ nr,
                          int* __restrict__ offs, int* __restrict__ list) {
  __shared__ int cnt[512], sc[512], cur[512];
  int tid = threadIdx.x;  // 512 threads
  cnt[tid] = 0;
  __syncthreads();
  for (int i = tid; i < 2 * kN; i += 512) {
    int r = (i < kN) ? pr[i] : nr[i - kN];
    atomicAdd(&cnt[r], 1);
  }
  __syncthreads();
  sc[tid] = cnt[tid];
  __syncthreads();
  for (int d = 1; d < 512; d <<= 1) {
    int v = (tid >= d) ? sc[tid - d] : 0;
    __syncthreads();
    sc[tid] += v;
    __syncthreads();
  }
  int excl = (tid == 0) ? 0 : sc[tid - 1];
  cur[tid] = excl;
  if (tid <= kREL) offs[tid] = excl;
  __syncthreads();
  for (int i = tid; i < 2 * kN; i += 512) {
    int r = (i < kN) ? pr[i] : nr[i - kN];
    int p = atomicAdd(&cur[r], 1);
    list[p] = i;
  }
}

// ---------------- scores: one block per RELATION ----------------
__global__ __launch_bounds__(256) void score_grouped(
    const float* __restrict__ ctx, const float* __restrict__ trans,
    const float* __restrict__ rel_embed,
    const int* __restrict__ ph, const int* __restrict__ pt,
    const int* __restrict__ nh, const int* __restrict__ nt,
    const int* __restrict__ offs, const int* __restrict__ list,
    float* __restrict__ scores) {
  int r = blockIdx.x;
  int start = offs[r], end = offs[r + 1];
  if (start >= end) return;
  int tid = threadIdx.x;
  __shared__ float cs[8][2][256];
  __shared__ float red[8][4];
  float relv = rel_embed[r * 256 + tid];
  const float4* Whp = (const float4*)(trans + (size_t)r * 65536 + (size_t)tid * 256);
  const float4* Wtp = (const float4*)(trans + ((size_t)r + kREL) * 65536 + (size_t)tid * 256);

  for (int chunk = start; chunk < end; chunk += 8) {
    int G = min(8, end - chunk);
    for (int j = 0; j < G; j++) {
      int i = list[chunk + j];
      int hh = (i < kN) ? ph[i] : nh[i - kN];
      int tt = (i < kN) ? pt[i] : nt[i - kN];
      cs[j][0][tid] = ctx[(size_t)hh * 256 + tid];
      cs[j][1][tid] = ctx[(size_t)tt * 256 + tid];
    }
    __syncthreads();
    float acc[8];
#pragma unroll
    for (int j = 0; j < 8; j++) acc[j] = relv;
#pragma unroll 2
    for (int q = 0; q < 64; q++) {
      float4 w1 = Whp[q];
      float4 w2 = Wtp[q];
#pragma unroll
      for (int j = 0; j < 8; j++) {
        float4 xh = *(const float4*)&cs[j][0][q * 4];
        float4 xt = *(const float4*)&cs[j][1][q * 4];
        acc[j] += w1.x * xh.x + w1.y * xh.y + w1.z * xh.z + w1.w * xh.w
                - (w2.x * xt.x + w2.y * xt.y + w2.z * xt.z + w2.w * xt.w);
      }
    }
    for (int j = 0; j < G; j++) {
      float sq = acc[j] * acc[j];
      for (int o = 32; o; o >>= 1) sq += __shfl_down(sq, o);
      if ((tid & 63) == 0) red[j][tid >> 6] = sq;
    }
    __syncthreads();
    if (tid < G) {
      float s = red[tid][0] + red[tid][1] + red[tid][2] + red[tid][3];
      scores[list[chunk + tid]] = sqrtf(s);
    }
    __syncthreads();
  }
}

__global__ void final_reduce(const float* __restrict__ scores, float* __restrict__ out) {
  int tid = threadIdx.x;
  float a = 0.f;
  for (int i = tid; i < 2 * kN; i += 256) {
    float s = scores[i];
    a += (i < kN) ? s : fmaxf(0.f, 1.f - s);
  }
  for (int off = 32; off; off >>= 1) a += __shfl_down(a, off);
  __shared__ float w4[4];
  if ((tid & 63) == 0) w4[tid >> 6] = a;
  __syncthreads();
  if (tid == 0) out[0] = w4[0] + w4[1] + w4[2] + w4[3];
}

// ---------------- host ----------------
extern "C" void kernel_launch(void* const* d_in, const int* in_sizes, int n_in,
                              void* d_out, int out_size, void* d_ws, size_t ws_size,
                              hipStream_t stream) {
  const int*   neighbors = (const int*)d_in[0];
  const int*   pos_h = (const int*)d_in[1];
  const int*   pos_t = (const int*)d_in[2];
  const int*   pos_r = (const int*)d_in[3];
  const int*   neg_h = (const int*)d_in[4];
  const int*   neg_t = (const int*)d_in[5];
  const int*   neg_r = (const int*)d_in[6];
  const float* ent_embed = (const float*)d_in[7];
  const float* rel_embed = (const float*)d_in[8];
  const float* trans = (const float*)d_in[9];
  const float* W_ih_f = (const float*)d_in[10];
  const float* W_hh_f = (const float*)d_in[11];
  const float* W_ih_b = (const float*)d_in[12];
  const float* W_hh_b = (const float*)d_in[13];
  const float* b_f = (const float*)d_in[14];
  const float* b_b = (const float*)d_in[15];
  const float* W_lin = (const float*)d_in[16];
  const float* b_lin = (const float*)d_in[17];
  const float* gamma = (const float*)d_in[18];
  const float* beta = (const float*)d_in[19];

  char* ws = (char*)d_ws;
  size_t off = 0;
  auto alloc = [&](size_t bytes) {
    void* p = ws + off;
    off = (off + bytes + 255) & ~(size_t)255;
    return p;
  };
  u16* Wihr   = (u16*)alloc((size_t)2 * 1024 * 256 * 2);      // 1 MB
  u16* Whhv   = (u16*)alloc((size_t)2 * 8 * 1024 * 32 * 2);   // 1 MB
  u16* Wlin   = (u16*)alloc((size_t)256 * kK * 2);            // 0.25 MB
  u16* x16    = (u16*)alloc((size_t)kS * kE * kD * 2);        // 32 MB
  u16* hio    = (u16*)alloc((size_t)2 * kE * kD * 2);         // 2 MB
  float* cio  = (float*)alloc((size_t)2 * kE * kD * 4);       // 4 MB
  float* lin  = (float*)alloc((size_t)kE * 256 * 4);
  float* part = (float*)alloc((size_t)2 * 64 * 256 * 4);
  float* ctx  = (float*)alloc((size_t)kE * 256 * 4);
  float* scores = (float*)alloc((size_t)2 * kN * 4);
  int* offsb  = (int*)alloc((size_t)512 * 4);
  int* list   = (int*)alloc((size_t)2 * kN * 4);
  size_t fixed_end = off;
  (void)in_sizes; (void)n_in; (void)out_size;

  // choose largest phase length T whose gates_x buffer fits the workspace
  int T = 2;
  for (int cand = 32; cand >= 2; cand >>= 1) {
    size_t gxb = (size_t)2 * cand * kE * 1024 * 2;
    if (fixed_end + gxb + (1 << 20) <= ws_size) { T = cand; break; }
  }
  u16* gx = (u16*)alloc((size_t)2 * T * kE * 1024 * 2);

  prep_weights<<<576, 256, 0, stream>>>(W_ih_f, W_hh_f, W_ih_b, W_hh_b, W_lin,
                                        Wihr, Whhv, Wlin);
  gather_x<<<4096, 256, 0, stream>>>(neighbors, ent_embed, x16);
  group_rel<<<1, 512, 0, stream>>>(pos_r, neg_r, offsb, list);

  for (int t0 = 0; t0 < kS; t0 += T) {
    xgemm<<<dim3(T * 32, 4, 2), 256, 0, stream>>>(x16, Wihr, b_f, b_b, gx, t0, T);
    lstm_rec<<<128, 512, 0, stream>>>(gx, Whhv, hio, cio, t0, T);
  }

  lin_kernel<<<32, 256, 0, stream>>>(hio, hio + (size_t)kE * kD, Wlin, b_lin, lin);
  bn_stats<<<64, 256, 0, stream>>>(lin, part);
  bn_apply<<<256, 256, 0, stream>>>(lin, part, gamma, beta, ctx);
  score_grouped<<<kREL, 256, 0, stream>>>(ctx, trans, rel_embed,
                                          pos_h, pos_t, neg_h, neg_t, offsb, list, scores);
  final_reduce<<<1, 256, 0, stream>>>(scores, (float*)d_out);
}

// Round 9
// 1048.860 us; speedup vs baseline: 1.0179x; 1.0179x over previous
//
#include <hip/hip_runtime.h>

// ---------------- constants ----------------
constexpr int kE   = 2048;   // entities
constexpr int kS   = 32;     // sequence length
constexpr int kD   = 256;    // ENT_DIM == REL_DIM == H
constexpr int kK   = 512;    // concat K (for lin)
constexpr int kREL = 500;
constexpr int kN   = 1024;   // triples per polarity

typedef unsigned short u16;
typedef __attribute__((ext_vector_type(8))) _Float16 f16x8;
typedef __attribute__((ext_vector_type(4))) float    f32x4;
typedef __attribute__((ext_vector_type(4))) unsigned short us4;

static __device__ __forceinline__ u16 f2h(float f) {
  _Float16 h = (_Float16)f;
  return __builtin_bit_cast(u16, h);
}
static __device__ __forceinline__ float h2f(u16 v) {
  _Float16 h = __builtin_bit_cast(_Float16, v);
  return (float)h;
}
static __device__ __forceinline__ float sigf(float x) { return 1.f / (1.f + __expf(-x)); }
static __device__ __forceinline__ float tanhfast(float x) {
  float e = __expf(2.f * x);
  return 1.f - 2.f / (e + 1.f);
}

// ---------------- prep: weights -> fp16 ----------------
// j-order (gate-interleaved): j -> gate g=(j>>4)&3, unit u=(j>>6)*16+(j&15), orig row R=g*256+u
// Wihr[d][j][256k] row-major; Whhv[d][c(8)][j(1024)][32k] chunk-major; Wlin[256][512] row-major
__global__ void prep_weights(const float* __restrict__ Wih_f, const float* __restrict__ Whh_f,
                             const float* __restrict__ Wih_b, const float* __restrict__ Whh_b,
                             const float* __restrict__ Wlin_in,
                             u16* __restrict__ Wihr, u16* __restrict__ Whhv,
                             u16* __restrict__ Wlin) {
  int idx = blockIdx.x * 256 + threadIdx.x;
  if (idx < 65536) {                       // Wihr: 2 x 32768 16B-units
    int d = idx >> 15;
    int j = (idx & 32767) >> 5;
    int k = (idx & 31) * 8;
    int g = (j >> 4) & 3, u = (j >> 6) * 16 + (j & 15);
    int R = g * 256 + u;
    const float* src = (d ? Wih_b : Wih_f) + R * 256 + k;
    ushort oa[8];
#pragma unroll
    for (int i = 0; i < 8; i++) oa[i] = f2h(src[i]);
    *(uint4*)((char*)Wihr + (size_t)idx * 16) = *(uint4*)oa;
  } else if (idx < 131072) {               // Whhv: 2 x 8 x 4096 16B-units
    int i = idx - 65536;
    int d = i >> 15;
    int rem = i & 32767;
    int c = rem >> 12;
    int P = (rem & 4095) * 16;
    int j = P >> 6, b = P & 63;
    int k = c * 32 + (b >> 1);
    int g = (j >> 4) & 3, u = (j >> 6) * 16 + (j & 15);
    int R = g * 256 + u;
    const float* src = (d ? Whh_b : Whh_f) + R * 256 + k;
    ushort oa[8];
#pragma unroll
    for (int ii = 0; ii < 8; ii++) oa[ii] = f2h(src[ii]);
    *(uint4*)((char*)Whhv + (size_t)i * 16) = *(uint4*)oa;
  } else if (idx < 131072 + 16384) {       // Wlin
    int q = (idx - 131072) * 8;
#pragma unroll
    for (int i = 0; i < 8; i++) Wlin[q + i] = f2h(Wlin_in[q + i]);
  }
}

// ---------------- gather x: x16[s][e][k] = fp16(ent_embed[neighbors[e][s]][k]) ----------------
__global__ void gather_x(const int* __restrict__ neighbors, const float* __restrict__ ent,
                         u16* __restrict__ x16) {
  const int tot = kS * kE * kD / 4;
  for (int i = blockIdx.x * blockDim.x + threadIdx.x; i < tot; i += gridDim.x * blockDim.x) {
    int k4 = i & 63;
    int row = i >> 6;               // s*kE + e
    int e = row & (kE - 1);
    int s = row >> 11;
    int nb = neighbors[e * kS + s];
    float4 v = *(const float4*)(ent + (size_t)nb * kD + k4 * 4);
    ushort4 o;
    o.x = f2h(v.x); o.y = f2h(v.y); o.z = f2h(v.z); o.w = f2h(v.w);
    *(ushort4*)(x16 + (size_t)row * kD + k4 * 4) = o;
  }
}

// ---------------- xgemm: gates_x = x @ W_ih^T + bias, for tt in [0,T) ----------------
// gx[dir][tt][e][u][4g] fp16 (bias folded in). grid (T*32, 4, 2), 256 thr.
__global__ __launch_bounds__(256) void xgemm(
    const u16* __restrict__ x16, const u16* __restrict__ Wihr,
    const float* __restrict__ b_f, const float* __restrict__ b_b,
    u16* __restrict__ gx, int t0, int T) {
  __shared__ __align__(16) char smem[40960];
  u16* As = (u16*)smem;
  u16* Bs = (u16*)(smem + 8192);
  const int tid = threadIdx.x, lane = tid & 63, w = tid >> 6;
  const int l15 = lane & 15, lq = lane >> 4;
  const int row0 = blockIdx.x * 64;
  const int y = blockIdx.y;
  const int dir = blockIdx.z;
  const int tt = row0 >> 11;
  const int e0 = row0 & 2047;
  const int s = dir ? (31 - (t0 + tt)) : (t0 + tt);
  const u16* Ab = x16 + ((size_t)s * kE + e0) * kD;
  const u16* Bb = Wihr + ((size_t)dir * 1024 + y * 256) * kD;
  const float* bd = dir ? b_b : b_f;
  const int u = (y * 4 + w) * 16 + l15;
  float bb4[4];
#pragma unroll
  for (int n = 0; n < 4; n++) bb4[n] = bd[n * 256 + u];

  f32x4 acc[4][4];
#pragma unroll
  for (int m = 0; m < 4; m++)
#pragma unroll
    for (int n = 0; n < 4; n++) acc[m][n] = (f32x4){0.f, 0.f, 0.f, 0.f};

  for (int ch = 0; ch < 4; ++ch) {
    const int k0 = ch * 64;
    __syncthreads();
#pragma unroll
    for (int i = 0; i < 2; i++) {
      int idx = tid + i * 256;
      int row = idx >> 3, c8 = idx & 7;
      uint4 v = *(const uint4*)(Ab + (size_t)row * kD + k0 + c8 * 8);
      *(uint4*)((char*)As + row * 128 + ((c8 * 16) ^ ((row & 7) << 4))) = v;
    }
#pragma unroll
    for (int i = 0; i < 8; i++) {
      int idx = tid + i * 256;
      int j = idx >> 3, c8 = idx & 7;
      uint4 v = *(const uint4*)(Bb + (size_t)j * kD + k0 + c8 * 8);
      *(uint4*)((char*)Bs + j * 128 + ((c8 * 16) ^ ((j & 7) << 4))) = v;
    }
    __syncthreads();
#pragma unroll
    for (int ks = 0; ks < 2; ++ks) {
      const int kb = ks * 64 + lq * 16;
      f16x8 a[4], b[4];
#pragma unroll
      for (int m = 0; m < 4; m++) {
        int row = m * 16 + l15;
        a[m] = *(const f16x8*)((const char*)As + row * 128 + (kb ^ ((row & 7) << 4)));
      }
#pragma unroll
      for (int n = 0; n < 4; n++) {
        int row = w * 64 + n * 16 + l15;
        b[n] = *(const f16x8*)((const char*)Bs + row * 128 + (kb ^ ((row & 7) << 4)));
      }
#pragma unroll
      for (int m = 0; m < 4; m++)
#pragma unroll
        for (int n = 0; n < 4; n++)
          acc[m][n] = __builtin_amdgcn_mfma_f32_16x16x32_f16(a[m], b[n], acc[m][n], 0, 0, 0);
    }
  }

  // store (+bias): g == n, one us4 per (m,r); non-temporal (read-once stream)
  u16* out = gx + (((size_t)dir * T + tt) * kE) * 1024;
#pragma unroll
  for (int m = 0; m < 4; m++)
#pragma unroll
    for (int r = 0; r < 4; r++) {
      int e = e0 + m * 16 + lq * 4 + r;
      us4 o;
      o[0] = f2h(acc[m][0][r] + bb4[0]); o[1] = f2h(acc[m][1][r] + bb4[1]);
      o[2] = f2h(acc[m][2][r] + bb4[2]); o[3] = f2h(acc[m][3][r] + bb4[3]);
      __builtin_nontemporal_store(o, (us4*)(out + ((size_t)e * 256 + u) * 4));
    }
}

// ---------------- recurrent kernel: h-GEMM (K=256) + gate combine, T steps ----------------
// grid 128 = 2dir x 64 etiles(32e); 1024 thr = 16 waves (4/SIMD); wave = 32e x 64j.
// acc[2][4]=32 + Wdbuf 32 + G 16 + creg 8 + a 8 + addr ~20 ≈ 116 VGPR <= 128.
__global__ __launch_bounds__(1024, 4) void lstm_rec(
    const u16* __restrict__ gx, const u16* __restrict__ Whhv,
    u16* __restrict__ hio, float* __restrict__ cio, int t0, int T) {
  __shared__ __align__(16) char hb[2][16384];
  const int tid = threadIdx.x, lane = tid & 63, w = tid >> 6;   // w in [0,16)
  const int l15 = lane & 15, lq = lane >> 4;
  const int bid = blockIdx.x;
  const int xcd = bid & 7;
  const int dir = xcd >> 2;                       // dir-per-XCD-half (W/XCD = 512 KB)
  const int e0 = ((bid >> 3) * 4 + (xcd & 3)) * 32;

  const char* Wd = (const char*)Whhv + (size_t)dir * 524288;   // [8c][1024j][64B]
  const u16* gxd = gx + (size_t)dir * T * kE * 1024;
  const int u = w * 16 + l15;

  // init h into hb[0] (swizzled): 1024 uint4 items, one per thread
  {
    int row = tid >> 5, c16 = tid & 31;
    uint4 v = {0, 0, 0, 0};
    if (t0 > 0) v = *(const uint4*)(hio + ((size_t)dir * kE + e0 + row) * kD + c16 * 8);
    *(uint4*)(hb[0] + row * 512 + ((c16 * 16) ^ ((row & 7) << 4))) = v;
  }
  float creg[2][4];
#pragma unroll
  for (int m = 0; m < 2; m++)
#pragma unroll
    for (int r = 0; r < 4; r++)
      creg[m][r] = (t0 > 0)
        ? cio[((size_t)dir * kE + e0 + m * 16 + lq * 4 + r) * kD + u] : 0.f;
  __syncthreads();

  // gx register buffer, one step ahead
  us4 G[2][4];
  auto gxload = [&](int t) {
    const u16* gp = gxd + (size_t)t * kE * 1024;
#pragma unroll
    for (int m = 0; m < 2; m++)
#pragma unroll
      for (int r = 0; r < 4; r++)
        G[m][r] = __builtin_nontemporal_load(
            (const us4*)(gp + (size_t)(e0 + m * 16 + lq * 4 + r) * 1024 + u * 4));
  };
  gxload(0);

  const int jb = (w * 64 + l15) * 64 + lq * 16;   // + n*1024 + c*65536

  int cur = 0;
  for (int t = 0; t < T; t++) {
    const char* hs = hb[cur];
    char* hn = hb[cur ^ 1];
    const bool hOut = (t == T - 1);

    // consume G into acc, then immediately prefetch next step's gx
    f32x4 acc[2][4];
#pragma unroll
    for (int m = 0; m < 2; m++)
#pragma unroll
      for (int g = 0; g < 4; g++)
#pragma unroll
        for (int r = 0; r < 4; r++)
          acc[m][g][r] = h2f(G[m][r][g]);
    if (t + 1 < T) gxload(t + 1);

    // GEMM over K=256 (8 chunks of 32), W double-buffered in registers
    f16x8 wA[4], wB[4];
#pragma unroll
    for (int n = 0; n < 4; n++)
      wA[n] = *(const f16x8*)(Wd + jb + n * 1024);
#pragma unroll
    for (int c = 0; c < 8; c++) {
      if (c + 1 < 8) {
#pragma unroll
        for (int n = 0; n < 4; n++) {
          f16x8 v = *(const f16x8*)(Wd + (size_t)(c + 1) * 65536 + jb + n * 1024);
          if (c & 1) wA[n] = v; else wB[n] = v;
        }
      }
      const int sb = (c * 32 + lq * 8) * 2;
      f16x8 a0, a1;
      { int row = l15;      a0 = *(const f16x8*)(hs + row * 512 + (sb ^ ((row & 7) << 4))); }
      { int row = 16 + l15; a1 = *(const f16x8*)(hs + row * 512 + (sb ^ ((row & 7) << 4))); }
#pragma unroll
      for (int n = 0; n < 4; n++) {
        const f16x8 wc = (c & 1) ? wB[n] : wA[n];
        acc[0][n] = __builtin_amdgcn_mfma_f32_16x16x32_f16(a0, wc, acc[0][n], 0, 0, 0);
        acc[1][n] = __builtin_amdgcn_mfma_f32_16x16x32_f16(a1, wc, acc[1][n], 0, 0, 0);
      }
    }

    // gate combine
#pragma unroll
    for (int m = 0; m < 2; m++)
#pragma unroll
      for (int r = 0; r < 4; r++) {
        float gi = acc[m][0][r];
        float gf = acc[m][1][r];
        float gg = acc[m][2][r];
        float go = acc[m][3][r];
        float cn = sigf(gf) * creg[m][r] + sigf(gi) * tanhfast(gg);
        creg[m][r] = cn;
        u16 hv = f2h(sigf(go) * tanhfast(cn));
        int row = m * 16 + lq * 4 + r;
        *(u16*)(hn + row * 512 + ((u * 2) ^ ((row & 7) << 4))) = hv;
        if (hOut) hio[((size_t)dir * kE + e0 + row) * kD + u] = hv;
      }
    __syncthreads();
    cur ^= 1;
  }

  if (t0 + T < kS) {
#pragma unroll
    for (int m = 0; m < 2; m++)
#pragma unroll
      for (int r = 0; r < 4; r++)
        cio[((size_t)dir * kE + e0 + m * 16 + lq * 4 + r) * kD + u] = creg[m][r];
  }
}

// ---------------- shared MFMA GEMM tile (used by lin): 64 rows x 256 cols, K=512 ----------------
static __device__ __forceinline__ void gemm_tile(
    const u16* __restrict__ Alo, const u16* __restrict__ Ahi,
    const u16* __restrict__ W, int e0,
    u16* As, u16* Bs, f32x4 (&acc)[4][4]) {
  const int tid = threadIdx.x;
  const int lane = tid & 63;
  const int w = tid >> 6;
#pragma unroll
  for (int m = 0; m < 4; m++)
#pragma unroll
    for (int n = 0; n < 4; n++) acc[m][n] = (f32x4){0.f, 0.f, 0.f, 0.f};

  for (int ch = 0; ch < 8; ++ch) {
    const int k0 = ch * 64;
    __syncthreads();
    const u16* Asrc = (k0 < 256) ? Alo : Ahi;
    const int kbase = (k0 < 256) ? k0 : (k0 - 256);
#pragma unroll
    for (int i = 0; i < 2; i++) {
      int idx = tid + i * 256;
      int row = idx >> 3, c8 = idx & 7;
      uint4 v = *(const uint4*)(Asrc + (size_t)(e0 + row) * 256 + kbase + c8 * 8);
      *(uint4*)((char*)As + row * 128 + ((c8 * 16) ^ ((row & 7) << 4))) = v;
    }
#pragma unroll
    for (int i = 0; i < 8; i++) {
      int idx = tid + i * 256;
      int j = idx >> 3, c8 = idx & 7;
      uint4 v = *(const uint4*)(W + (size_t)j * kK + k0 + c8 * 8);
      *(uint4*)((char*)Bs + j * 128 + ((c8 * 16) ^ ((j & 7) << 4))) = v;
    }
    __syncthreads();
#pragma unroll
    for (int ks = 0; ks < 2; ++ks) {
      const int kb = ks * 64 + (lane >> 4) * 16;
      f16x8 a[4], b[4];
#pragma unroll
      for (int m = 0; m < 4; m++) {
        int row = m * 16 + (lane & 15);
        a[m] = *(const f16x8*)((const char*)As + row * 128 + (kb ^ ((row & 7) << 4)));
      }
#pragma unroll
      for (int n = 0; n < 4; n++) {
        int row = w * 64 + n * 16 + (lane & 15);
        b[n] = *(const f16x8*)((const char*)Bs + row * 128 + (kb ^ ((row & 7) << 4)));
      }
#pragma unroll
      for (int m = 0; m < 4; m++)
#pragma unroll
        for (int n = 0; n < 4; n++)
          acc[m][n] = __builtin_amdgcn_mfma_f32_16x16x32_f16(a[m], b[n], acc[m][n], 0, 0, 0);
    }
  }
}

// ---------------- lin = [h_f | h_b] @ W_lin^T + b_lin ----------------
__global__ __launch_bounds__(256) void lin_kernel(
    const u16* __restrict__ hf, const u16* __restrict__ hb,
    const u16* __restrict__ Wl, const float* __restrict__ b_lin,
    float* __restrict__ lin) {
  __shared__ __align__(16) char smem[40960];
  u16* As = (u16*)smem;
  u16* Bs = (u16*)(smem + 8192);
  const int tid = threadIdx.x, lane = tid & 63, w = tid >> 6;
  const int e0 = blockIdx.x * 64;
  f32x4 acc[4][4];
  gemm_tile(hf, hb, Wl, e0, As, Bs, acc);
#pragma unroll
  for (int m = 0; m < 4; m++)
#pragma unroll
    for (int n = 0; n < 4; n++)
#pragma unroll
      for (int r = 0; r < 4; r++) {
        int e = e0 + m * 16 + (lane >> 4) * 4 + r;
        int col = w * 64 + n * 16 + (lane & 15);
        lin[(size_t)e * 256 + col] = acc[m][n][r] + b_lin[col];
      }
}

// ---------------- BatchNorm stats (training mode, biased var) ----------------
__global__ void bn_stats(const float* __restrict__ lin, float* __restrict__ part) {
  int b = blockIdx.x, c = threadIdx.x;  // grid 64, each 32 rows
  float s = 0.f, s2 = 0.f;
  for (int e = b * 32; e < b * 32 + 32; ++e) {
    float x = lin[(size_t)e * 256 + c];
    s += x; s2 += x * x;
  }
  part[b * 256 + c] = s;
  part[64 * 256 + b * 256 + c] = s2;
}

// ---------------- BN finalize (inline) + tanh ----------------
__global__ void bn_apply(const float* __restrict__ lin, const float* __restrict__ part,
                         const float* __restrict__ gamma, const float* __restrict__ beta,
                         float* __restrict__ ctx) {
  int c = threadIdx.x;                   // grid 256, each 8 rows
  float s = 0.f, s2 = 0.f;
  for (int b = 0; b < 64; b++) { s += part[b * 256 + c]; s2 += part[64 * 256 + b * 256 + c]; }
  float mu = s * (1.f / 2048.f);
  float rsig = rsqrtf(s2 * (1.f / 2048.f) - mu * mu + 1e-5f);
  float ga = gamma[c], be = beta[c];
  int e0 = blockIdx.x * 8;
  for (int e = e0; e < e0 + 8; ++e) {
    float x = lin[(size_t)e * 256 + c];
    ctx[(size_t)e * 256 + c] = tanhf(ga * (x - mu) * rsig + be);
  }
}

// ---------------- relation grouping: count+scan+scatter in ONE block ----------------
__global__ void group_rel(const int* __restrict__ pr, const int* __restrict__ nr,
                          int* __restrict__ offs, int* __restrict__ list) {
  __shared__ int cnt[512], sc[512], cur[512];
  int tid = threadIdx.x;  // 512 threads
  cnt[tid] = 0;
  __syncthreads();
  for (int i = tid; i < 2 * kN; i += 512) {
    int r = (i < kN) ? pr[i] : nr[i - kN];
    atomicAdd(&cnt[r], 1);
  }
  __syncthreads();
  sc[tid] = cnt[tid];
  __syncthreads();
  for (int d = 1; d < 512; d <<= 1) {
    int v = (tid >= d) ? sc[tid - d] : 0;
    __syncthreads();
    sc[tid] += v;
    __syncthreads();
  }
  int excl = (tid == 0) ? 0 : sc[tid - 1];
  cur[tid] = excl;
  if (tid <= kREL) offs[tid] = excl;
  __syncthreads();
  for (int i = tid; i < 2 * kN; i += 512) {
    int r = (i < kN) ? pr[i] : nr[i - kN];
    int p = atomicAdd(&cur[r], 1);
    list[p] = i;
  }
}

// ---------------- scores: one block per RELATION ----------------
__global__ __launch_bounds__(256) void score_grouped(
    const float* __restrict__ ctx, const float* __restrict__ trans,
    const float* __restrict__ rel_embed,
    const int* __restrict__ ph, const int* __restrict__ pt,
    const int* __restrict__ nh, const int* __restrict__ nt,
    const int* __restrict__ offs, const int* __restrict__ list,
    float* __restrict__ scores) {
  int r = blockIdx.x;
  int start = offs[r], end = offs[r + 1];
  if (start >= end) return;
  int tid = threadIdx.x;
  __shared__ float cs[8][2][256];
  __shared__ float red[8][4];
  float relv = rel_embed[r * 256 + tid];
  const float4* Whp = (const float4*)(trans + (size_t)r * 65536 + (size_t)tid * 256);
  const float4* Wtp = (const float4*)(trans + ((size_t)r + kREL) * 65536 + (size_t)tid * 256);

  for (int chunk = start; chunk < end; chunk += 8) {
    int G = min(8, end - chunk);
    for (int j = 0; j < G; j++) {
      int i = list[chunk + j];
      int hh = (i < kN) ? ph[i] : nh[i - kN];
      int tt = (i < kN) ? pt[i] : nt[i - kN];
      cs[j][0][tid] = ctx[(size_t)hh * 256 + tid];
      cs[j][1][tid] = ctx[(size_t)tt * 256 + tid];
    }
    __syncthreads();
    float acc[8];
#pragma unroll
    for (int j = 0; j < 8; j++) acc[j] = relv;
#pragma unroll 2
    for (int q = 0; q < 64; q++) {
      float4 w1 = Whp[q];
      float4 w2 = Wtp[q];
#pragma unroll
      for (int j = 0; j < 8; j++) {
        float4 xh = *(const float4*)&cs[j][0][q * 4];
        float4 xt = *(const float4*)&cs[j][1][q * 4];
        acc[j] += w1.x * xh.x + w1.y * xh.y + w1.z * xh.z + w1.w * xh.w
                - (w2.x * xt.x + w2.y * xt.y + w2.z * xt.z + w2.w * xt.w);
      }
    }
    for (int j = 0; j < G; j++) {
      float sq = acc[j] * acc[j];
      for (int o = 32; o; o >>= 1) sq += __shfl_down(sq, o);
      if ((tid & 63) == 0) red[j][tid >> 6] = sq;
    }
    __syncthreads();
    if (tid < G) {
      float s = red[tid][0] + red[tid][1] + red[tid][2] + red[tid][3];
      scores[list[chunk + tid]] = sqrtf(s);
    }
    __syncthreads();
  }
}

__global__ void final_reduce(const float* __restrict__ scores, float* __restrict__ out) {
  int tid = threadIdx.x;
  float a = 0.f;
  for (int i = tid; i < 2 * kN; i += 256) {
    float s = scores[i];
    a += (i < kN) ? s : fmaxf(0.f, 1.f - s);
  }
  for (int off = 32; off; off >>= 1) a += __shfl_down(a, off);
  __shared__ float w4[4];
  if ((tid & 63) == 0) w4[tid >> 6] = a;
  __syncthreads();
  if (tid == 0) out[0] = w4[0] + w4[1] + w4[2] + w4[3];
}

// ---------------- host ----------------
extern "C" void kernel_launch(void* const* d_in, const int* in_sizes, int n_in,
                              void* d_out, int out_size, void* d_ws, size_t ws_size,
                              hipStream_t stream) {
  const int*   neighbors = (const int*)d_in[0];
  const int*   pos_h = (const int*)d_in[1];
  const int*   pos_t = (const int*)d_in[2];
  const int*   pos_r = (const int*)d_in[3];
  const int*   neg_h = (const int*)d_in[4];
  const int*   neg_t = (const int*)d_in[5];
  const int*   neg_r = (const int*)d_in[6];
  const float* ent_embed = (const float*)d_in[7];
  const float* rel_embed = (const float*)d_in[8];
  const float* trans = (const float*)d_in[9];
  const float* W_ih_f = (const float*)d_in[10];
  const float* W_hh_f = (const float*)d_in[11];
  const float* W_ih_b = (const float*)d_in[12];
  const float* W_hh_b = (const float*)d_in[13];
  const float* b_f = (const float*)d_in[14];
  const float* b_b = (const float*)d_in[15];
  const float* W_lin = (const float*)d_in[16];
  const float* b_lin = (const float*)d_in[17];
  const float* gamma = (const float*)d_in[18];
  const float* beta = (const float*)d_in[19];

  char* ws = (char*)d_ws;
  size_t off = 0;
  auto alloc = [&](size_t bytes) {
    void* p = ws + off;
    off = (off + bytes + 255) & ~(size_t)255;
    return p;
  };
  u16* Wihr   = (u16*)alloc((size_t)2 * 1024 * 256 * 2);      // 1 MB
  u16* Whhv   = (u16*)alloc((size_t)2 * 8 * 1024 * 32 * 2);   // 1 MB
  u16* Wlin   = (u16*)alloc((size_t)256 * kK * 2);            // 0.25 MB
  u16* x16    = (u16*)alloc((size_t)kS * kE * kD * 2);        // 32 MB
  u16* hio    = (u16*)alloc((size_t)2 * kE * kD * 2);         // 2 MB
  float* cio  = (float*)alloc((size_t)2 * kE * kD * 4);       // 4 MB
  float* lin  = (float*)alloc((size_t)kE * 256 * 4);
  float* part = (float*)alloc((size_t)2 * 64 * 256 * 4);
  float* ctx  = (float*)alloc((size_t)kE * 256 * 4);
  float* scores = (float*)alloc((size_t)2 * kN * 4);
  int* offsb  = (int*)alloc((size_t)512 * 4);
  int* list   = (int*)alloc((size_t)2 * kN * 4);
  size_t fixed_end = off;
  (void)in_sizes; (void)n_in; (void)out_size;

  // choose largest phase length T whose gates_x buffer fits the workspace
  int T = 2;
  for (int cand = 32; cand >= 2; cand >>= 1) {
    size_t gxb = (size_t)2 * cand * kE * 1024 * 2;
    if (fixed_end + gxb + (1 << 20) <= ws_size) { T = cand; break; }
  }
  u16* gx = (u16*)alloc((size_t)2 * T * kE * 1024 * 2);

  prep_weights<<<576, 256, 0, stream>>>(W_ih_f, W_hh_f, W_ih_b, W_hh_b, W_lin,
                                        Wihr, Whhv, Wlin);
  gather_x<<<4096, 256, 0, stream>>>(neighbors, ent_embed, x16);
  group_rel<<<1, 512, 0, stream>>>(pos_r, neg_r, offsb, list);

  for (int t0 = 0; t0 < kS; t0 += T) {
    xgemm<<<dim3(T * 32, 4, 2), 256, 0, stream>>>(x16, Wihr, b_f, b_b, gx, t0, T);
    lstm_rec<<<128, 1024, 0, stream>>>(gx, Whhv, hio, cio, t0, T);
  }

  lin_kernel<<<32, 256, 0, stream>>>(hio, hio + (size_t)kE * kD, Wlin, b_lin, lin);
  bn_stats<<<64, 256, 0, stream>>>(lin, part);
  bn_apply<<<256, 256, 0, stream>>>(lin, part, gamma, beta, ctx);
  score_grouped<<<kREL, 256, 0, stream>>>(ctx, trans, rel_embed,
                                          pos_h, pos_t, neg_h, neg_t, offsb, list, scores);
  final_reduce<<<1, 256, 0, stream>>>(scores, (float*)d_out);
}

// Round 10
// 825.203 us; speedup vs baseline: 1.2938x; 1.2710x over previous
//
#include <hip/hip_runtime.h>

// ---------------- constants ----------------
constexpr int kE   = 2048;   // entities
constexpr int kS   = 32;     // sequence length
constexpr int kD   = 256;    // ENT_DIM == REL_DIM == H
constexpr int kK   = 512;    // concat K (for lin)
constexpr int kREL = 500;
constexpr int kN   = 1024;   // triples per polarity

typedef unsigned short u16;
typedef __attribute__((ext_vector_type(8))) _Float16 f16x8;
typedef __attribute__((ext_vector_type(4))) float    f32x4;
typedef __attribute__((ext_vector_type(4))) unsigned short us4;

static __device__ __forceinline__ u16 f2h(float f) {
  _Float16 h = (_Float16)f;
  return __builtin_bit_cast(u16, h);
}
static __device__ __forceinline__ float h2f(u16 v) {
  _Float16 h = __builtin_bit_cast(_Float16, v);
  return (float)h;
}
static __device__ __forceinline__ float sigf(float x) { return 1.f / (1.f + __expf(-x)); }
static __device__ __forceinline__ float tanhfast(float x) {
  float e = __expf(2.f * x);
  return 1.f - 2.f / (e + 1.f);
}

// ---------------- prep: weights -> fp16, gate-interleaved j-order, row-major ----------------
// j -> gate g=(j>>4)&3, unit u=(j>>6)*16+(j&15), orig row R=g*256+u
// Wihr[d][j][256k], Whhr[d][j][256k], Wlin[256][512]
__global__ void prep_weights(const float* __restrict__ Wih_f, const float* __restrict__ Whh_f,
                             const float* __restrict__ Wih_b, const float* __restrict__ Whh_b,
                             const float* __restrict__ Wlin_in,
                             u16* __restrict__ Wihr, u16* __restrict__ Whhr,
                             u16* __restrict__ Wlin) {
  int idx = blockIdx.x * 256 + threadIdx.x;
  if (idx < 65536) {                       // Wihr: 2 x 1024j x 32 16B-units
    int d = idx >> 15;
    int j = (idx & 32767) >> 5;
    int k = (idx & 31) * 8;
    int g = (j >> 4) & 3, u = (j >> 6) * 16 + (j & 15);
    int R = g * 256 + u;
    const float* src = (d ? Wih_b : Wih_f) + R * 256 + k;
    ushort oa[8];
#pragma unroll
    for (int i = 0; i < 8; i++) oa[i] = f2h(src[i]);
    *(uint4*)((char*)Wihr + (size_t)idx * 16) = *(uint4*)oa;
  } else if (idx < 131072) {               // Whhr: same layout for W_hh
    int i2 = idx - 65536;
    int d = i2 >> 15;
    int j = (i2 & 32767) >> 5;
    int k = (i2 & 31) * 8;
    int g = (j >> 4) & 3, u = (j >> 6) * 16 + (j & 15);
    int R = g * 256 + u;
    const float* src = (d ? Whh_b : Whh_f) + R * 256 + k;
    ushort oa[8];
#pragma unroll
    for (int i = 0; i < 8; i++) oa[i] = f2h(src[i]);
    *(uint4*)((char*)Whhr + (size_t)i2 * 16) = *(uint4*)oa;
  } else if (idx < 131072 + 16384) {       // Wlin
    int q = (idx - 131072) * 8;
#pragma unroll
    for (int i = 0; i < 8; i++) Wlin[q + i] = f2h(Wlin_in[q + i]);
  }
}

// ---------------- gather x: x16[s][e][k] = fp16(ent_embed[neighbors[e][s]][k]) ----------------
__global__ void gather_x(const int* __restrict__ neighbors, const float* __restrict__ ent,
                         u16* __restrict__ x16) {
  const int tot = kS * kE * kD / 4;
  for (int i = blockIdx.x * blockDim.x + threadIdx.x; i < tot; i += gridDim.x * blockDim.x) {
    int k4 = i & 63;
    int row = i >> 6;               // s*kE + e
    int e = row & (kE - 1);
    int s = row >> 11;
    int nb = neighbors[e * kS + s];
    float4 v = *(const float4*)(ent + (size_t)nb * kD + k4 * 4);
    ushort4 o;
    o.x = f2h(v.x); o.y = f2h(v.y); o.z = f2h(v.z); o.w = f2h(v.w);
    *(ushort4*)(x16 + (size_t)row * kD + k4 * 4) = o;
  }
}

// ---------------- xgemm: gates_x = x @ W_ih^T + bias, for tt in [0,T) ----------------
// gx[dir][tt][e][u][4g] fp16 (bias folded in). grid (T*32, 4, 2), 256 thr.
__global__ __launch_bounds__(256) void xgemm(
    const u16* __restrict__ x16, const u16* __restrict__ Wihr,
    const float* __restrict__ b_f, const float* __restrict__ b_b,
    u16* __restrict__ gx, int t0, int T) {
  __shared__ __align__(16) char smem[40960];
  u16* As = (u16*)smem;
  u16* Bs = (u16*)(smem + 8192);
  const int tid = threadIdx.x, lane = tid & 63, w = tid >> 6;
  const int l15 = lane & 15, lq = lane >> 4;
  const int row0 = blockIdx.x * 64;
  const int y = blockIdx.y;
  const int dir = blockIdx.z;
  const int tt = row0 >> 11;
  const int e0 = row0 & 2047;
  const int s = dir ? (31 - (t0 + tt)) : (t0 + tt);
  const u16* Ab = x16 + ((size_t)s * kE + e0) * kD;
  const u16* Bb = Wihr + ((size_t)dir * 1024 + y * 256) * kD;
  const float* bd = dir ? b_b : b_f;
  const int u = (y * 4 + w) * 16 + l15;
  float bb4[4];
#pragma unroll
  for (int n = 0; n < 4; n++) bb4[n] = bd[n * 256 + u];

  f32x4 acc[4][4];
#pragma unroll
  for (int m = 0; m < 4; m++)
#pragma unroll
    for (int n = 0; n < 4; n++) acc[m][n] = (f32x4){0.f, 0.f, 0.f, 0.f};

  for (int ch = 0; ch < 4; ++ch) {
    const int k0 = ch * 64;
    __syncthreads();
#pragma unroll
    for (int i = 0; i < 2; i++) {
      int idx = tid + i * 256;
      int row = idx >> 3, c8 = idx & 7;
      uint4 v = *(const uint4*)(Ab + (size_t)row * kD + k0 + c8 * 8);
      *(uint4*)((char*)As + row * 128 + ((c8 * 16) ^ ((row & 7) << 4))) = v;
    }
#pragma unroll
    for (int i = 0; i < 8; i++) {
      int idx = tid + i * 256;
      int j = idx >> 3, c8 = idx & 7;
      uint4 v = *(const uint4*)(Bb + (size_t)j * kD + k0 + c8 * 8);
      *(uint4*)((char*)Bs + j * 128 + ((c8 * 16) ^ ((j & 7) << 4))) = v;
    }
    __syncthreads();
#pragma unroll
    for (int ks = 0; ks < 2; ++ks) {
      const int kb = ks * 64 + lq * 16;
      f16x8 a[4], b[4];
#pragma unroll
      for (int m = 0; m < 4; m++) {
        int row = m * 16 + l15;
        a[m] = *(const f16x8*)((const char*)As + row * 128 + (kb ^ ((row & 7) << 4)));
      }
#pragma unroll
      for (int n = 0; n < 4; n++) {
        int row = w * 64 + n * 16 + l15;
        b[n] = *(const f16x8*)((const char*)Bs + row * 128 + (kb ^ ((row & 7) << 4)));
      }
#pragma unroll
      for (int m = 0; m < 4; m++)
#pragma unroll
        for (int n = 0; n < 4; n++)
          acc[m][n] = __builtin_amdgcn_mfma_f32_16x16x32_f16(a[m], b[n], acc[m][n], 0, 0, 0);
    }
  }

  u16* out = gx + (((size_t)dir * T + tt) * kE) * 1024;
#pragma unroll
  for (int m = 0; m < 4; m++)
#pragma unroll
    for (int r = 0; r < 4; r++) {
      int e = e0 + m * 16 + lq * 4 + r;
      us4 o;
      o[0] = f2h(acc[m][0][r] + bb4[0]); o[1] = f2h(acc[m][1][r] + bb4[1]);
      o[2] = f2h(acc[m][2][r] + bb4[2]); o[3] = f2h(acc[m][3][r] + bb4[3]);
      __builtin_nontemporal_store(o, (us4*)(out + ((size_t)e * 256 + u) * 4));
    }
}

// ---------------- one LSTM step, h-half only (K=256), round-3 structure ----------------
// grid 256 = (dir(2), ut(8), et(16)); 256 thr, 4 waves; wave = 64e x 64j.
// No LDS, no barriers: acc init from gx, A/B direct global->reg, c fp32 global round-trip.
__global__ __launch_bounds__(256) void lstm_step(
    const u16* __restrict__ gx, const u16* __restrict__ Whhr,
    const u16* __restrict__ hprev, u16* __restrict__ hnext,
    float* __restrict__ cbuf, int tt, int T) {
  const int tid = threadIdx.x, lane = tid & 63, w = tid >> 6;
  const int l15 = lane & 15, lq = lane >> 4;
  const int bid = blockIdx.x;
  const int dir = bid >> 7;
  const int ut  = (bid >> 4) & 7;
  const int et  = bid & 15;
  const int wr = w >> 1, wc = w & 1;
  const int e0 = et * 128 + wr * 64;
  const int c0 = ut * 128 + wc * 64;
  const int unit = (c0 >> 6) * 16 + l15;

  const u16* Wd  = Whhr + (size_t)dir * 1024 * kD;
  const u16* hpd = hprev + (size_t)dir * kE * kD;
  u16* hnd = hnext + (size_t)dir * kE * kD;
  float* cd = cbuf + (size_t)dir * kE * kD;
  const u16* gp = gx + ((size_t)dir * T + tt) * kE * 1024;

  // init acc from gates_x (bias already folded)
  f32x4 acc[4][4];
#pragma unroll
  for (int m = 0; m < 4; m++)
#pragma unroll
    for (int r = 0; r < 4; r++) {
      us4 g = __builtin_nontemporal_load(
          (const us4*)(gp + (size_t)(e0 + m * 16 + lq * 4 + r) * 1024 + unit * 4));
#pragma unroll
      for (int n = 0; n < 4; n++) acc[m][n][r] = h2f(g[n]);
    }

  const int klane = lq * 8;
#pragma unroll
  for (int ks = 0; ks < 8; ks++) {
    const int ka = ks * 32 + klane;
    f16x8 a[4], b[4];
#pragma unroll
    for (int m = 0; m < 4; m++)
      a[m] = *(const f16x8*)(hpd + (size_t)(e0 + m * 16 + l15) * kD + ka);
#pragma unroll
    for (int n = 0; n < 4; n++)
      b[n] = *(const f16x8*)(Wd + (size_t)(c0 + n * 16 + l15) * kD + ka);
#pragma unroll
    for (int m = 0; m < 4; m++)
#pragma unroll
      for (int n = 0; n < 4; n++)
        acc[m][n] = __builtin_amdgcn_mfma_f32_16x16x32_f16(a[m], b[n], acc[m][n], 0, 0, 0);
  }

#pragma unroll
  for (int m = 0; m < 4; m++)
#pragma unroll
    for (int r = 0; r < 4; r++) {
      int row = e0 + m * 16 + lq * 4 + r;
      size_t off = (size_t)row * kD + unit;
      float gi = acc[m][0][r];
      float gf = acc[m][1][r];
      float gg = acc[m][2][r];
      float go = acc[m][3][r];
      float c_old = cd[off];
      float cn = sigf(gf) * c_old + sigf(gi) * tanhfast(gg);
      cd[off] = cn;
      hnd[off] = f2h(sigf(go) * tanhfast(cn));
    }
}

// ---------------- shared MFMA GEMM tile (used by lin): 64 rows x 256 cols, K=512 ----------------
static __device__ __forceinline__ void gemm_tile(
    const u16* __restrict__ Alo, const u16* __restrict__ Ahi,
    const u16* __restrict__ W, int e0,
    u16* As, u16* Bs, f32x4 (&acc)[4][4]) {
  const int tid = threadIdx.x;
  const int lane = tid & 63;
  const int w = tid >> 6;
#pragma unroll
  for (int m = 0; m < 4; m++)
#pragma unroll
    for (int n = 0; n < 4; n++) acc[m][n] = (f32x4){0.f, 0.f, 0.f, 0.f};

  for (int ch = 0; ch < 8; ++ch) {
    const int k0 = ch * 64;
    __syncthreads();
    const u16* Asrc = (k0 < 256) ? Alo : Ahi;
    const int kbase = (k0 < 256) ? k0 : (k0 - 256);
#pragma unroll
    for (int i = 0; i < 2; i++) {
      int idx = tid + i * 256;
      int row = idx >> 3, c8 = idx & 7;
      uint4 v = *(const uint4*)(Asrc + (size_t)(e0 + row) * 256 + kbase + c8 * 8);
      *(uint4*)((char*)As + row * 128 + ((c8 * 16) ^ ((row & 7) << 4))) = v;
    }
#pragma unroll
    for (int i = 0; i < 8; i++) {
      int idx = tid + i * 256;
      int j = idx >> 3, c8 = idx & 7;
      uint4 v = *(const uint4*)(W + (size_t)j * kK + k0 + c8 * 8);
      *(uint4*)((char*)Bs + j * 128 + ((c8 * 16) ^ ((j & 7) << 4))) = v;
    }
    __syncthreads();
#pragma unroll
    for (int ks = 0; ks < 2; ++ks) {
      const int kb = ks * 64 + (lane >> 4) * 16;
      f16x8 a[4], b[4];
#pragma unroll
      for (int m = 0; m < 4; m++) {
        int row = m * 16 + (lane & 15);
        a[m] = *(const f16x8*)((const char*)As + row * 128 + (kb ^ ((row & 7) << 4)));
      }
#pragma unroll
      for (int n = 0; n < 4; n++) {
        int row = w * 64 + n * 16 + (lane & 15);
        b[n] = *(const f16x8*)((const char*)Bs + row * 128 + (kb ^ ((row & 7) << 4)));
      }
#pragma unroll
      for (int m = 0; m < 4; m++)
#pragma unroll
        for (int n = 0; n < 4; n++)
          acc[m][n] = __builtin_amdgcn_mfma_f32_16x16x32_f16(a[m], b[n], acc[m][n], 0, 0, 0);
    }
  }
}

// ---------------- lin = [h_f | h_b] @ W_lin^T + b_lin ----------------
__global__ __launch_bounds__(256) void lin_kernel(
    const u16* __restrict__ hf, const u16* __restrict__ hb,
    const u16* __restrict__ Wl, const float* __restrict__ b_lin,
    float* __restrict__ lin) {
  __shared__ __align__(16) char smem[40960];
  u16* As = (u16*)smem;
  u16* Bs = (u16*)(smem + 8192);
  const int tid = threadIdx.x, lane = tid & 63, w = tid >> 6;
  const int e0 = blockIdx.x * 64;
  f32x4 acc[4][4];
  gemm_tile(hf, hb, Wl, e0, As, Bs, acc);
#pragma unroll
  for (int m = 0; m < 4; m++)
#pragma unroll
    for (int n = 0; n < 4; n++)
#pragma unroll
      for (int r = 0; r < 4; r++) {
        int e = e0 + m * 16 + (lane >> 4) * 4 + r;
        int col = w * 64 + n * 16 + (lane & 15);
        lin[(size_t)e * 256 + col] = acc[m][n][r] + b_lin[col];
      }
}

// ---------------- BatchNorm stats (training mode, biased var) ----------------
__global__ void bn_stats(const float* __restrict__ lin, float* __restrict__ part) {
  int b = blockIdx.x, c = threadIdx.x;  // grid 64, each 32 rows
  float s = 0.f, s2 = 0.f;
  for (int e = b * 32; e < b * 32 + 32; ++e) {
    float x = lin[(size_t)e * 256 + c];
    s += x; s2 += x * x;
  }
  part[b * 256 + c] = s;
  part[64 * 256 + b * 256 + c] = s2;
}

// ---------------- BN finalize (inline) + tanh ----------------
__global__ void bn_apply(const float* __restrict__ lin, const float* __restrict__ part,
                         const float* __restrict__ gamma, const float* __restrict__ beta,
                         float* __restrict__ ctx) {
  int c = threadIdx.x;                   // grid 256, each 8 rows
  float s = 0.f, s2 = 0.f;
  for (int b = 0; b < 64; b++) { s += part[b * 256 + c]; s2 += part[64 * 256 + b * 256 + c]; }
  float mu = s * (1.f / 2048.f);
  float rsig = rsqrtf(s2 * (1.f / 2048.f) - mu * mu + 1e-5f);
  float ga = gamma[c], be = beta[c];
  int e0 = blockIdx.x * 8;
  for (int e = e0; e < e0 + 8; ++e) {
    float x = lin[(size_t)e * 256 + c];
    ctx[(size_t)e * 256 + c] = tanhf(ga * (x - mu) * rsig + be);
  }
}

// ---------------- relation grouping: count+scan+scatter in ONE block ----------------
__global__ void group_rel(const int* __restrict__ pr, const int* __restrict__ nr,
                          int* __restrict__ offs, int* __restrict__ list) {
  __shared__ int cnt[512], sc[512], cur[512];
  int tid = threadIdx.x;  // 512 threads
  cnt[tid] = 0;
  __syncthreads();
  for (int i = tid; i < 2 * kN; i += 512) {
    int r = (i < kN) ? pr[i] : nr[i - kN];
    atomicAdd(&cnt[r], 1);
  }
  __syncthreads();
  sc[tid] = cnt[tid];
  __syncthreads();
  for (int d = 1; d < 512; d <<= 1) {
    int v = (tid >= d) ? sc[tid - d] : 0;
    __syncthreads();
    sc[tid] += v;
    __syncthreads();
  }
  int excl = (tid == 0) ? 0 : sc[tid - 1];
  cur[tid] = excl;
  if (tid <= kREL) offs[tid] = excl;
  __syncthreads();
  for (int i = tid; i < 2 * kN; i += 512) {
    int r = (i < kN) ? pr[i] : nr[i - kN];
    int p = atomicAdd(&cur[r], 1);
    list[p] = i;
  }
}

// ---------------- scores: one block per RELATION ----------------
__global__ __launch_bounds__(256) void score_grouped(
    const float* __restrict__ ctx, const float* __restrict__ trans,
    const float* __restrict__ rel_embed,
    const int* __restrict__ ph, const int* __restrict__ pt,
    const int* __restrict__ nh, const int* __restrict__ nt,
    const int* __restrict__ offs, const int* __restrict__ list,
    float* __restrict__ scores) {
  int r = blockIdx.x;
  int start = offs[r], end = offs[r + 1];
  if (start >= end) return;
  int tid = threadIdx.x;
  __shared__ float cs[8][2][256];
  __shared__ float red[8][4];
  float relv = rel_embed[r * 256 + tid];
  const float4* Whp = (const float4*)(trans + (size_t)r * 65536 + (size_t)tid * 256);
  const float4* Wtp = (const float4*)(trans + ((size_t)r + kREL) * 65536 + (size_t)tid * 256);

  for (int chunk = start; chunk < end; chunk += 8) {
    int G = min(8, end - chunk);
    for (int j = 0; j < G; j++) {
      int i = list[chunk + j];
      int hh = (i < kN) ? ph[i] : nh[i - kN];
      int tt = (i < kN) ? pt[i] : nt[i - kN];
      cs[j][0][tid] = ctx[(size_t)hh * 256 + tid];
      cs[j][1][tid] = ctx[(size_t)tt * 256 + tid];
    }
    __syncthreads();
    float acc[8];
#pragma unroll
    for (int j = 0; j < 8; j++) acc[j] = relv;
#pragma unroll 2
    for (int q = 0; q < 64; q++) {
      float4 w1 = Whp[q];
      float4 w2 = Wtp[q];
#pragma unroll
      for (int j = 0; j < 8; j++) {
        float4 xh = *(const float4*)&cs[j][0][q * 4];
        float4 xt = *(const float4*)&cs[j][1][q * 4];
        acc[j] += w1.x * xh.x + w1.y * xh.y + w1.z * xh.z + w1.w * xh.w
                - (w2.x * xt.x + w2.y * xt.y + w2.z * xt.z + w2.w * xt.w);
      }
    }
    for (int j = 0; j < G; j++) {
      float sq = acc[j] * acc[j];
      for (int o = 32; o; o >>= 1) sq += __shfl_down(sq, o);
      if ((tid & 63) == 0) red[j][tid >> 6] = sq;
    }
    __syncthreads();
    if (tid < G) {
      float s = red[tid][0] + red[tid][1] + red[tid][2] + red[tid][3];
      scores[list[chunk + tid]] = sqrtf(s);
    }
    __syncthreads();
  }
}

__global__ void final_reduce(const float* __restrict__ scores, float* __restrict__ out) {
  int tid = threadIdx.x;
  float a = 0.f;
  for (int i = tid; i < 2 * kN; i += 256) {
    float s = scores[i];
    a += (i < kN) ? s : fmaxf(0.f, 1.f - s);
  }
  for (int off = 32; off; off >>= 1) a += __shfl_down(a, off);
  __shared__ float w4[4];
  if ((tid & 63) == 0) w4[tid >> 6] = a;
  __syncthreads();
  if (tid == 0) out[0] = w4[0] + w4[1] + w4[2] + w4[3];
}

// ---------------- host ----------------
extern "C" void kernel_launch(void* const* d_in, const int* in_sizes, int n_in,
                              void* d_out, int out_size, void* d_ws, size_t ws_size,
                              hipStream_t stream) {
  const int*   neighbors = (const int*)d_in[0];
  const int*   pos_h = (const int*)d_in[1];
  const int*   pos_t = (const int*)d_in[2];
  const int*   pos_r = (const int*)d_in[3];
  const int*   neg_h = (const int*)d_in[4];
  const int*   neg_t = (const int*)d_in[5];
  const int*   neg_r = (const int*)d_in[6];
  const float* ent_embed = (const float*)d_in[7];
  const float* rel_embed = (const float*)d_in[8];
  const float* trans = (const float*)d_in[9];
  const float* W_ih_f = (const float*)d_in[10];
  const float* W_hh_f = (const float*)d_in[11];
  const float* W_ih_b = (const float*)d_in[12];
  const float* W_hh_b = (const float*)d_in[13];
  const float* b_f = (const float*)d_in[14];
  const float* b_b = (const float*)d_in[15];
  const float* W_lin = (const float*)d_in[16];
  const float* b_lin = (const float*)d_in[17];
  const float* gamma = (const float*)d_in[18];
  const float* beta = (const float*)d_in[19];

  char* ws = (char*)d_ws;
  size_t off = 0;
  auto alloc = [&](size_t bytes) {
    void* p = ws + off;
    off = (off + bytes + 255) & ~(size_t)255;
    return p;
  };
  u16* Wihr   = (u16*)alloc((size_t)2 * 1024 * kD * 2);       // 1 MB
  u16* Whhr   = (u16*)alloc((size_t)2 * 1024 * kD * 2);       // 1 MB
  u16* Wlin   = (u16*)alloc((size_t)256 * kK * 2);            // 0.25 MB
  u16* x16    = (u16*)alloc((size_t)kS * kE * kD * 2);        // 32 MB
  u16* h0     = (u16*)alloc((size_t)2 * kE * kD * 2);         // 2 MB
  u16* h1     = (u16*)alloc((size_t)2 * kE * kD * 2);         // 2 MB
  float* cbuf = (float*)alloc((size_t)2 * kE * kD * 4);       // 4 MB
  float* lin  = (float*)alloc((size_t)kE * 256 * 4);
  float* part = (float*)alloc((size_t)2 * 64 * 256 * 4);
  float* ctx  = (float*)alloc((size_t)kE * 256 * 4);
  float* scores = (float*)alloc((size_t)2 * kN * 4);
  int* offsb  = (int*)alloc((size_t)512 * 4);
  int* list   = (int*)alloc((size_t)2 * kN * 4);
  size_t fixed_end = off;
  (void)in_sizes; (void)n_in; (void)out_size;

  // choose largest phase length T whose gates_x buffer fits the workspace
  int T = 2;
  for (int cand = 32; cand >= 2; cand >>= 1) {
    size_t gxb = (size_t)2 * cand * kE * 1024 * 2;
    if (fixed_end + gxb + (1 << 20) <= ws_size) { T = cand; break; }
  }
  u16* gx = (u16*)alloc((size_t)2 * T * kE * 1024 * 2);

  hipMemsetAsync(h0, 0, (size_t)2 * kE * kD * 2, stream);
  hipMemsetAsync(cbuf, 0, (size_t)2 * kE * kD * 4, stream);

  prep_weights<<<576, 256, 0, stream>>>(W_ih_f, W_hh_f, W_ih_b, W_hh_b, W_lin,
                                        Wihr, Whhr, Wlin);
  gather_x<<<4096, 256, 0, stream>>>(neighbors, ent_embed, x16);
  group_rel<<<1, 512, 0, stream>>>(pos_r, neg_r, offsb, list);

  for (int t0 = 0; t0 < kS; t0 += T) {
    xgemm<<<dim3(T * 32, 4, 2), 256, 0, stream>>>(x16, Wihr, b_f, b_b, gx, t0, T);
    for (int tt = 0; tt < T; tt++) {
      int t = t0 + tt;
      const u16* hp = (t & 1) ? h1 : h0;
      u16* hn = (t & 1) ? h0 : h1;
      lstm_step<<<256, 256, 0, stream>>>(gx, Whhr, hp, hn, cbuf, tt, T);
    }
  }

  // after t=31 (odd), final h (both dirs) is in h0
  lin_kernel<<<32, 256, 0, stream>>>(h0, h0 + (size_t)kE * kD, Wlin, b_lin, lin);
  bn_stats<<<64, 256, 0, stream>>>(lin, part);
  bn_apply<<<256, 256, 0, stream>>>(lin, part, gamma, beta, ctx);
  score_grouped<<<kREL, 256, 0, stream>>>(ctx, trans, rel_embed,
                                          pos_h, pos_t, neg_h, neg_t, offsb, list, scores);
  final_reduce<<<1, 256, 0, stream>>>(scores, (float*)d_out);
}